// Round 9
// baseline (71.813 us; speedup 1.0000x reference)
//
#include <hip/hip_runtime.h>

// Output: (224, 2, 257, 600) f32.  out plane pl = b*56 + (2*p + s), pairs from
// triu_indices(8, k=1). INVERTED decomposition: each block reads one chunk of
// one (batch, channel) ONCE and NT-stores it to all 7 destination planes.
// c_dst[c] = the 7 in-batch plane slots (2*p+s) consuming channel c.
__device__ __constant__ int c_dst[8][7] = {
    { 0,  2,  4,  6,  8, 10, 12},   // c=0: ref of pairs (0,1)..(0,7)
    { 1, 14, 16, 18, 20, 22, 24},   // c=1: tgt of (0,1); ref of (1,2)..(1,7)
    { 3, 15, 26, 28, 30, 32, 34},   // c=2
    { 5, 17, 27, 36, 38, 40, 42},   // c=3
    { 7, 19, 29, 37, 44, 46, 48},   // c=4
    { 9, 21, 31, 39, 45, 50, 52},   // c=5
    {11, 23, 33, 41, 47, 51, 54},   // c=6
    {13, 25, 35, 43, 49, 53, 55},   // c=7: tgt of (0,7)..(6,7)
};

typedef float f32x4 __attribute__((ext_vector_type(4)));

#define PLANE4 38550   // 257*600/4 float4 per plane
#define GRIDX  38      // chunks per channel
#define TPP    (GRIDX * 256)   // 9728 float4 per k-stripe

__global__ void scatter7_kernel(const f32x4* __restrict__ in,
                                f32x4* __restrict__ out) {
    unsigned w     = blockIdx.x;
    unsigned b     = w & 7u;          // batch == XCD (round-robin affinity)
    unsigned local = w >> 3;          // 0..303
    unsigned c     = local / 38u;     // channel 0..7 (magic-mul)
    unsigned chunk = local - c * 38u; // 0..37

    const f32x4* __restrict__ src  = in  + (size_t)((b << 3) + c) * PLANE4;
    f32x4*       __restrict__ outb = out + (size_t)b * 56u * PLANE4;

    int t  = (int)chunk * 256 + (int)threadIdx.x;   // 0..9727
    int i0 = t;
    int i1 = t + TPP;
    int i2 = t + 2 * TPP;
    int i3 = t + 3 * TPP;          // max 38911 >= 38550 -> guard
    bool p3 = i3 < PLANE4;

    // Read ONCE (4-deep MLP) ...
    f32x4 v0 = src[i0];
    f32x4 v1 = src[i1];
    f32x4 v2 = src[i2];
    f32x4 v3;
    if (p3) v3 = src[i3];

    // ... scatter to the 7 consuming planes. c is block-uniform -> the table
    // lookups are scalar loads; dst bases live in SGPRs.
#pragma unroll
    for (int m = 0; m < 7; ++m) {
        f32x4* __restrict__ dst = outb + (size_t)c_dst[c][m] * PLANE4;
        __builtin_nontemporal_store(v0, &dst[i0]);
        __builtin_nontemporal_store(v1, &dst[i1]);
        __builtin_nontemporal_store(v2, &dst[i2]);
        if (p3) __builtin_nontemporal_store(v3, &dst[i3]);
    }
}

extern "C" void kernel_launch(void* const* d_in, const int* in_sizes, int n_in,
                              void* d_out, int out_size, void* d_ws, size_t ws_size,
                              hipStream_t stream) {
    const f32x4* in  = (const f32x4*)d_in[0];
    f32x4*       out = (f32x4*)d_out;
    dim3 block(256, 1, 1);
    dim3 grid(8 * 8 * GRIDX, 1, 1);   // 2432 blocks: batch x channel x chunk
    scatter7_kernel<<<grid, block, 0, stream>>>(in, out);
}

// Round 10
// 65.225 us; speedup vs baseline: 1.1010x; 1.1010x over previous
//
#include <hip/hip_runtime.h>

// Output: (224, 2, 257, 600) f32.  plane pl = b*56 + 2*p + s, pl in [0,448)
// src channel per (2*p+s) from triu_indices(8, k=1) pair table.
__device__ __constant__ int c_ch[56] = {
    0,1, 0,2, 0,3, 0,4, 0,5, 0,6, 0,7,
    1,2, 1,3, 1,4, 1,5, 1,6, 1,7,
    2,3, 2,4, 2,5, 2,6, 2,7,
    3,4, 3,5, 3,6, 3,7,
    4,5, 4,6, 4,7,
    5,6, 5,7,
    6,7
};

typedef float f32x4 __attribute__((ext_vector_type(4)));

#define PLANE4 38550   // 257*600/4 float4 per plane (plane = 616800 B, mod 128 = 96)
#define GRIDX  38      // chunks per plane
#define TPP    (GRIDX * 256)   // 9728 threads per plane; 9728*16 B % 128 == 0

// R7 structure (batch==XCD affinity, plane-major walk, peel alignment, 4-deep
// MLP) with PLAIN stores: full-line aligned bursts write-allocate in L2 with
// no RFO (fill kernel: FETCH~0 at 6.9 TB/s) and drain at the L2 eviction rate,
// vs NT bypass whose drain rate appears capped (~4.8 TB/s observed).
__global__ void gather_pairs_kernel(const f32x4* __restrict__ in,
                                    f32x4* __restrict__ out) {
    unsigned w     = blockIdx.x;
    unsigned b     = w & 7u;          // batch == XCD
    unsigned local = w >> 3;          // 0..2127
    unsigned pib   = local / 38u;     // plane in batch, 0..55 (magic-mul)
    unsigned chunk = local - pib * 38u;
    unsigned pl    = b * 56u + pib;
    unsigned ch    = (unsigned)c_ch[pib];   // wave-uniform scalar load

    const f32x4* __restrict__ src = in  + (size_t)((b << 3) + ch) * PLANE4;
    f32x4*       __restrict__ dst = out + (size_t)pl * PLANE4;

    // plane base mod 128 cycles with pl&3: 0,96,64,32. Peel leading float4s
    // so bulk accesses are 128-B line-aligned (loads AND stores).
    int off  = ((pl & 3) * 96) & 127;
    int peel = ((128 - off) & 127) >> 4;   // 0, 2, 4, or 6 float4s

    int t = chunk * 256 + threadIdx.x;     // 0..9727
    if (t < peel) {
        dst[t] = src[t];
    }

    // 4-deep MLP: all loads issued before any store waits on them.
    int i0 = peel + t;
    int i1 = i0 + TPP;
    int i2 = i1 + TPP;
    int i3 = i2 + TPP;
    bool p3 = i3 < PLANE4;

    f32x4 v0 = src[i0];
    f32x4 v1 = src[i1];
    f32x4 v2 = src[i2];
    f32x4 v3;
    if (p3) v3 = src[i3];

    dst[i0] = v0;
    dst[i1] = v1;
    dst[i2] = v2;
    if (p3) dst[i3] = v3;
}

extern "C" void kernel_launch(void* const* d_in, const int* in_sizes, int n_in,
                              void* d_out, int out_size, void* d_ws, size_t ws_size,
                              hipStream_t stream) {
    const f32x4* in  = (const f32x4*)d_in[0];
    f32x4*       out = (f32x4*)d_out;
    dim3 block(256, 1, 1);
    dim3 grid(8 * 56 * GRIDX, 1, 1);   // 17024 blocks, batch-affine, plane-major
    gather_pairs_kernel<<<grid, block, 0, stream>>>(in, out);
}

// Round 11
// 57.638 us; speedup vs baseline: 1.2459x; 1.1316x over previous
//
#include <hip/hip_runtime.h>

// Output: (224, 2, 257, 600) f32.  plane pl = b*56 + 2*p + s, pl in [0,448)
// src channel per (2*p+s) from triu_indices(8, k=1) pair table.
__device__ __constant__ int c_ch[56] = {
    0,1, 0,2, 0,3, 0,4, 0,5, 0,6, 0,7,
    1,2, 1,3, 1,4, 1,5, 1,6, 1,7,
    2,3, 2,4, 2,5, 2,6, 2,7,
    3,4, 3,5, 3,6, 3,7,
    4,5, 4,6, 4,7,
    5,6, 5,7,
    6,7
};

typedef float f32x4 __attribute__((ext_vector_type(4)));

#define PLANE4 38550   // 257*600/4 float4 per plane (plane = 616800 B, mod 128 = 96)
#define GRIDX  19      // chunks per plane (was 38): 2x work per thread
#define TPP    (GRIDX * 256)   // 4864 threads per plane; 4864*16 B % 128 == 0
#define EPT    8               // float4 per thread

// R7 structure (batch==XCD affinity, plane-major, peel, NT stores) with EPT=8:
// half the blocks, 8-deep load+store queues per wave -> less block churn,
// deeper steady-state store queue toward the fill kernel's regime.
__global__ void gather_pairs_kernel(const f32x4* __restrict__ in,
                                    f32x4* __restrict__ out) {
    unsigned w     = blockIdx.x;
    unsigned b     = w & 7u;          // batch == XCD
    unsigned local = w >> 3;          // 0..1063
    unsigned pib   = local / 19u;     // plane in batch, 0..55 (magic-mul)
    unsigned chunk = local - pib * 19u;   // 0..18
    unsigned pl    = b * 56u + pib;
    unsigned ch    = (unsigned)c_ch[pib];   // wave-uniform scalar load

    const f32x4* __restrict__ src = in  + (size_t)((b << 3) + ch) * PLANE4;
    f32x4*       __restrict__ dst = out + (size_t)pl * PLANE4;

    // plane base mod 128 cycles with pl&3: 0,96,64,32. Peel leading float4s
    // so bulk accesses are 128-B line-aligned (loads AND stores).
    int off  = ((pl & 3) * 96) & 127;
    int peel = ((128 - off) & 127) >> 4;   // 0, 2, 4, or 6 float4s

    int t = chunk * 256 + threadIdx.x;     // 0..4863
    if (t < peel) {
        f32x4 v = src[t];
        __builtin_nontemporal_store(v, &dst[t]);
    }

    // 8-deep MLP: all 8 loads issued before any store waits on them.
    // k=0..6 provably in-range (max 6+4863+6*4864 = 34053 < 38550); k=7 guarded.
    int  idx[EPT];
    f32x4 v[EPT];
#pragma unroll
    for (int k = 0; k < EPT; ++k) idx[k] = peel + t + k * TPP;
    bool p7 = idx[EPT - 1] < PLANE4;

#pragma unroll
    for (int k = 0; k < EPT - 1; ++k) v[k] = src[idx[k]];
    if (p7) v[EPT - 1] = src[idx[EPT - 1]];

#pragma unroll
    for (int k = 0; k < EPT - 1; ++k)
        __builtin_nontemporal_store(v[k], &dst[idx[k]]);
    if (p7) __builtin_nontemporal_store(v[EPT - 1], &dst[idx[EPT - 1]]);
}

extern "C" void kernel_launch(void* const* d_in, const int* in_sizes, int n_in,
                              void* d_out, int out_size, void* d_ws, size_t ws_size,
                              hipStream_t stream) {
    const f32x4* in  = (const f32x4*)d_in[0];
    f32x4*       out = (f32x4*)d_out;
    dim3 block(256, 1, 1);
    dim3 grid(8 * 56 * GRIDX, 1, 1);   // 8512 blocks, batch-affine, plane-major
    gather_pairs_kernel<<<grid, block, 0, stream>>>(in, out);
}

// Round 12
// 52.130 us; speedup vs baseline: 1.3776x; 1.1057x over previous
//
#include <hip/hip_runtime.h>

// Output: (224, 2, 257, 600) f32.  plane pl = b*56 + slot, slot = 2*p + s,
// pairs from triu_indices(8, k=1). c_ch[slot] = source channel.
__device__ __constant__ int c_ch[56] = {
    0,1, 0,2, 0,3, 0,4, 0,5, 0,6, 0,7,
    1,2, 1,3, 1,4, 1,5, 1,6, 1,7,
    2,3, 2,4, 2,5, 2,6, 2,7,
    3,4, 3,5, 3,6, 3,7,
    4,5, 4,6, 4,7,
    5,6, 5,7,
    6,7
};

// Clique-ordered pair walk: groups {0123},{01x45},{23x45},{4567},{01x67},{23x67}
// -> any two adjacent groups span only 6 channels (3.7 MB < 4 MB L2/XCD).
// c_seq[k] = pair index p processed at sequence position k.
__device__ __constant__ int c_seq[28] = {
     0,  1,  2,  7,  8, 13,    // G1: pairs inside {0,1,2,3}
     3,  4,  9, 10,            // G2: {0,1} x {4,5}
    14, 15, 18, 19,            // G3: {2,3} x {4,5}
    22, 23, 24, 25, 26, 27,    // G6: pairs inside {4,5,6,7}
     5,  6, 11, 12,            // G4: {0,1} x {6,7}
    16, 17, 20, 21             // G5: {2,3} x {6,7}
};

typedef float f32x4 __attribute__((ext_vector_type(4)));

#define PLANE4 38550   // 257*600/4 float4 per plane (plane = 616800 B, mod 128 = 96)
#define GRIDX  19      // chunks per plane
#define TPP    (GRIDX * 256)   // 4864 threads per plane; 4864*16 B % 128 == 0
#define EPT    8               // float4 per thread

__global__ void gather_pairs_kernel(const f32x4* __restrict__ in,
                                    f32x4* __restrict__ out) {
    unsigned w     = blockIdx.x;
    unsigned b     = w & 7u;          // batch == XCD
    unsigned local = w >> 3;          // 0..1063
    unsigned seq   = local / 19u;     // sequence position 0..55 (magic-mul)
    unsigned chunk = local - seq * 19u;     // 0..18
    // seq -> in-batch plane slot via clique order: pair c_seq[seq>>1], s=seq&1
    unsigned slot  = 2u * (unsigned)c_seq[seq >> 1] + (seq & 1u);
    unsigned pl    = b * 56u + slot;
    unsigned ch    = (unsigned)c_ch[slot];  // wave-uniform scalar load

    const f32x4* __restrict__ src = in  + (size_t)((b << 3) + ch) * PLANE4;
    f32x4*       __restrict__ dst = out + (size_t)pl * PLANE4;

    // plane base mod 128 cycles with pl&3: 0,96,64,32. Peel leading float4s
    // so bulk accesses are 128-B line-aligned (loads AND stores).
    int off  = ((pl & 3) * 96) & 127;
    int peel = ((128 - off) & 127) >> 4;   // 0, 2, 4, or 6 float4s

    int t = chunk * 256 + threadIdx.x;     // 0..4863
    if (t < peel) {
        f32x4 v = src[t];
        __builtin_nontemporal_store(v, &dst[t]);
    }

    // 8-deep MLP: all 8 loads issued before any store waits on them.
    // k=0..6 provably in-range (max 6+4863+6*4864 = 34053 < 38550); k=7 guarded.
    int  idx[EPT];
    f32x4 v[EPT];
#pragma unroll
    for (int k = 0; k < EPT; ++k) idx[k] = peel + t + k * TPP;
    bool p7 = idx[EPT - 1] < PLANE4;

#pragma unroll
    for (int k = 0; k < EPT - 1; ++k) v[k] = src[idx[k]];
    if (p7) v[EPT - 1] = src[idx[EPT - 1]];

#pragma unroll
    for (int k = 0; k < EPT - 1; ++k)
        __builtin_nontemporal_store(v[k], &dst[idx[k]]);
    if (p7) __builtin_nontemporal_store(v[EPT - 1], &dst[idx[EPT - 1]]);
}

extern "C" void kernel_launch(void* const* d_in, const int* in_sizes, int n_in,
                              void* d_out, int out_size, void* d_ws, size_t ws_size,
                              hipStream_t stream) {
    const f32x4* in  = (const f32x4*)d_in[0];
    f32x4*       out = (f32x4*)d_out;
    dim3 block(256, 1, 1);
    dim3 grid(8 * 56 * GRIDX, 1, 1);   // 8512 blocks, batch-affine, clique order
    gather_pairs_kernel<<<grid, block, 0, stream>>>(in, out);
}